// Round 19
// baseline (58.968 us; speedup 1.0000x reference)
//
#include <hip/hip_runtime.h>
#include <hip/hip_bf16.h>

constexpr int HID = 1024;
constexpr int KD  = 16;    // probe directions
constexpr int TM  = 16;    // rows per tile
constexpr int NW  = 8;     // waves per block (each owns a 128-wide col slice)
constexpr int TPB = 8;     // tiles per block (2048 tiles / 256 blocks)

typedef short bf16x8 __attribute__((ext_vector_type(8)));   // MFMA A/B frag
typedef float f32x4  __attribute__((ext_vector_type(4)));   // MFMA C/D frag

__device__ __forceinline__ short f2b(float x) {
    __hip_bfloat16 b = __float2bfloat16(x);
    return *reinterpret_cast<short*>(&b);
}
__device__ __forceinline__ float b2f(short s) {
    return __uint_as_float(((unsigned int)(unsigned short)s) << 16);
}

#define SCHED_FENCE() __builtin_amdgcn_sched_barrier(0)

// Stage one 64KB H tile via global_load_lds: wave w stages rows w*2..w*2+1.
// 16B-piece swizzle ^ (row&7) applied on the GLOBAL source address (LDS dest
// linear, as required); coef ds_read applies the same XOR.
__device__ __forceinline__ void stage_tile(float* ldsBuf, const float* Hbase,
                                           int w, int lane) {
    #pragma unroll
    for (int i = 0; i < 8; ++i) {
        const int rr = w*2 + (i >> 2);
        const int qq = i & 3;
        const int s  = qq*64 + lane;                  // lds piece slot
        const float* g = Hbase + rr*1024 + ((s ^ (rr & 7)) << 2);
        const float* l = ldsBuf + rr*1024 + qq*256;   // wave-uniform base; HW adds lane*16
        __builtin_amdgcn_global_load_lds(
            (const __attribute__((address_space(1))) void*)g,
            (__attribute__((address_space(3))) void*)l, 16, 0, 0);
    }
}

// R19 = R18 (51.1 us) + NONTEMPORAL output stores. R18's FETCH=66MB shows
// half of H already lives in L3 across replays; the 131MB of write-allocating
// plain stores is what evicts the other half. Since R13 each 128B out line is
// fully covered by one store instruction (4 q-lanes x 32B), nt stores are
// full-line-safe (R9's nt failure was 64B split lines). Expect H to become
// fully L3-resident: FETCH -> <20MB.
__global__ __launch_bounds__(NW*64)
void probe_removal_nt(const float* __restrict__ H,
                      const float* __restrict__ Qf,
                      float* __restrict__ out)
{
    const int lane = threadIdx.x & 63;
    const int w    = threadIdx.x >> 6;   // wave: col slice [w*128, w*128+128)
    const int r    = lane & 15;
    const int q    = lane >> 4;

    __shared__ __align__(16) float Hb[2][TM][HID];   // 128 KB double buffer
    __shared__ __align__(16) float ctr[NW][TM][20];  // coef partials
    __shared__ float s2p[NW][TM];

    const int tile0 = blockIdx.x * TPB;

    // ---- persistent Q fragments gathered directly from Qf (single launch) ----
    // coef B-frag: bq[kt][i] = bf16(Q[k][r]), k = w*128 + kt*32 + q*8 + i
    bf16x8 bq[4];
    #pragma unroll
    for (int kt = 0; kt < 4; ++kt)
        #pragma unroll
        for (int i = 0; i < 8; ++i)
            bq[kt][i] = f2b(Qf[(w*128 + kt*32 + q*8 + i)*KD + r]);
    // epilogue A-frags (R13-verified permutation, R15 geometry):
    // pair p: col0 = w*128 + p*32 + (r>>2)*8 + (r&3), col1 = col0 + 4;
    // aq0[p][i] = bf16(Q[col0][q*8+i]) -> two contiguous float4 loads each.
    bf16x8 aq0[4], aq1[4];
    #pragma unroll
    for (int p = 0; p < 4; ++p) {
        if (q < 2) {
            const int col0 = w*128 + p*32 + ((r >> 2) << 3) + (r & 3);
            const float* s0 = Qf + col0*KD + q*8;
            const float* s1 = Qf + (col0 + 4)*KD + q*8;
            const float4 x0 = *reinterpret_cast<const float4*>(s0);
            const float4 y0 = *reinterpret_cast<const float4*>(s0 + 4);
            const float4 x1 = *reinterpret_cast<const float4*>(s1);
            const float4 y1 = *reinterpret_cast<const float4*>(s1 + 4);
            aq0[p][0]=f2b(x0.x); aq0[p][1]=f2b(x0.y); aq0[p][2]=f2b(x0.z); aq0[p][3]=f2b(x0.w);
            aq0[p][4]=f2b(y0.x); aq0[p][5]=f2b(y0.y); aq0[p][6]=f2b(y0.z); aq0[p][7]=f2b(y0.w);
            aq1[p][0]=f2b(x1.x); aq1[p][1]=f2b(x1.y); aq1[p][2]=f2b(x1.z); aq1[p][3]=f2b(x1.w);
            aq1[p][4]=f2b(y1.x); aq1[p][5]=f2b(y1.y); aq1[p][6]=f2b(y1.z); aq1[p][7]=f2b(y1.w);
        } else {
            #pragma unroll
            for (int i = 0; i < 8; ++i) { aq0[p][i] = 0; aq1[p][i] = 0; }
        }
    }
    SCHED_FENCE();

    // ---- prologue: stage tiles 0 and 1 (8 loads each per wave) ----
    stage_tile(&Hb[0][0][0], H + (size_t)tile0*TM*HID, w, lane);
    SCHED_FENCE();
    stage_tile(&Hb[1][0][0], H + (size_t)(tile0+1)*TM*HID, w, lane);
    SCHED_FENCE();
    asm volatile("s_waitcnt vmcnt(8)" ::: "memory");   // tile 0 landed (tile 1 in flight)
    SCHED_FENCE();
    __builtin_amdgcn_s_barrier();

    #pragma unroll
    for (int t = 0; t < TPB; ++t) {
        const int cur = t & 1;
        const char* HbC = (const char*)&Hb[cur][0][0];

        // ---- coef GEMM from LDS (swizzled b128 reads); af = h slice in regs ----
        bf16x8 af[4];
        f32x4 acc0 = {0.f,0.f,0.f,0.f}, acc1 = {0.f,0.f,0.f,0.f};
        float s2 = 0.f;
        #pragma unroll
        for (int kt = 0; kt < 4; ++kt) {
            const int P  = w*32 + kt*8 + q*2;       // even piece index
            const int sx = P ^ (r & 7);
            const float4 x = *(const float4*)(HbC + r*4096 + sx*16);
            const float4 y = *(const float4*)(HbC + r*4096 + (sx^1)*16);
            s2 = fmaf(x.x,x.x, fmaf(x.y,x.y, fmaf(x.z,x.z, fmaf(x.w,x.w, s2))));
            s2 = fmaf(y.x,y.x, fmaf(y.y,y.y, fmaf(y.z,y.z, fmaf(y.w,y.w, s2))));
            bf16x8 a;
            a[0]=f2b(x.x); a[1]=f2b(x.y); a[2]=f2b(x.z); a[3]=f2b(x.w);
            a[4]=f2b(y.x); a[5]=f2b(y.y); a[6]=f2b(y.z); a[7]=f2b(y.w);
            af[kt] = a;
            if (kt & 1) acc1 = __builtin_amdgcn_mfma_f32_16x16x32_bf16(a, bq[kt], acc1, 0, 0, 0);
            else        acc0 = __builtin_amdgcn_mfma_f32_16x16x32_bf16(a, bq[kt], acc0, 0, 0, 0);
        }
        const f32x4 acc = acc0 + acc1;
        s2 += __shfl_xor(s2, 16);
        s2 += __shfl_xor(s2, 32);

        #pragma unroll
        for (int i = 0; i < 4; ++i) ctr[w][q*4 + i][r] = acc[i];
        if (q == 0) s2p[w][r] = s2;

        // ctr visible to all waves; raw barrier does NOT drain vmcnt:
        asm volatile("s_waitcnt lgkmcnt(0)" ::: "memory");
        SCHED_FENCE();
        __builtin_amdgcn_s_barrier();
        SCHED_FENCE();

        // ---- stage tile t+2 into the freed buffer ----
        if (t + 2 < TPB)
            stage_tile(&Hb[cur][0][0], H + (size_t)(tile0+t+2)*TM*HID, w, lane);
        SCHED_FENCE();

        // ---- cross-wave reduce -> coefs, scale, pb ----
        float cf[8] = {0,0,0,0,0,0,0,0};
        if (q < 2) {
            #pragma unroll
            for (int w2 = 0; w2 < NW; ++w2) {
                const float4 a = *reinterpret_cast<const float4*>(&ctr[w2][r][q*8]);
                const float4 b = *reinterpret_cast<const float4*>(&ctr[w2][r][q*8 + 4]);
                cf[0]+=a.x; cf[1]+=a.y; cf[2]+=a.z; cf[3]+=a.w;
                cf[4]+=b.x; cf[5]+=b.y; cf[6]+=b.z; cf[7]+=b.w;
            }
        }
        float s2tot = 0.f;
        #pragma unroll
        for (int w2 = 0; w2 < NW; ++w2) s2tot += s2p[w2][r];

        float sc2 = 0.f;
        #pragma unroll
        for (int i = 0; i < 8; ++i) sc2 = fmaf(cf[i], cf[i], sc2);
        sc2 += __shfl_xor(sc2, 16);
        sc2 += __shfl_xor(sc2, 32);
        const float scale = rsqrtf(fmaxf(1.0f - sc2 / s2tot, 1e-20f));

        bf16x8 pb;
        #pragma unroll
        for (int i = 0; i < 8; ++i) pb[i] = f2b(cf[i]);

        // ---- fused epilogue: all operands in registers; 8 nt stores/lane ----
        float* orow = out + (size_t)(tile0+t)*TM*HID + r*HID + w*128;
        const f32x4 zero4 = {0.f,0.f,0.f,0.f};
        #pragma unroll
        for (int p = 0; p < 4; ++p) {
            const f32x4 d0 = __builtin_amdgcn_mfma_f32_16x16x32_bf16(aq0[p], pb, zero4, 0, 0, 0);
            const f32x4 d1 = __builtin_amdgcn_mfma_f32_16x16x32_bf16(aq1[p], pb, zero4, 0, 0, 0);
            f32x4 o0, o1;
            #pragma unroll
            for (int ii = 0; ii < 4; ++ii) {
                o0[ii] = (b2f(af[p][ii])     - d0[ii]) * scale;
                o1[ii] = (b2f(af[p][4 + ii]) - d1[ii]) * scale;
            }
            // NONTEMPORAL: no L2/L3 write-allocate -> H stays L3-resident.
            // Full-line safe: lanes q=0..3 of this one instruction cover the
            // entire 128B line (cols p*32 + q*8 + 0..7).
            __builtin_nontemporal_store(o0, reinterpret_cast<f32x4*>(orow + p*32 + q*8));
            __builtin_nontemporal_store(o1, reinterpret_cast<f32x4*>(orow + p*32 + q*8 + 4));
        }
        SCHED_FENCE();

        // ---- counted drain: stage(t+1) landed; stage(t+2)+stores(t) stay
        //      in flight (never vmcnt(0) mid-loop) ----
        if (t < TPB-1) {
            asm volatile("s_waitcnt vmcnt(16)" ::: "memory");
            SCHED_FENCE();
            __builtin_amdgcn_s_barrier();
            SCHED_FENCE();
        }
    }
}

extern "C" void kernel_launch(void* const* d_in, const int* in_sizes, int n_in,
                              void* d_out, int out_size, void* d_ws, size_t ws_size,
                              hipStream_t stream) {
    const float* H  = (const float*)d_in[0];   // [8,4096,1024] f32
    const float* Qf = (const float*)d_in[1];   // [1024,16] f32, orthonormal cols
    float* outp     = (float*)d_out;
    const int nrows  = in_sizes[0] / HID;      // 32768
    const int ntiles = nrows / TM;             // 2048

    // SINGLE launch: 139KB LDS -> 1 block/CU, 256 blocks x 8 tiles, DMA pipeline
    hipLaunchKernelGGL(probe_removal_nt, dim3(ntiles / TPB), dim3(NW*64), 0, stream,
                       H, Qf, outp);
}

// Round 20
// 53.631 us; speedup vs baseline: 1.0995x; 1.0995x over previous
//
#include <hip/hip_runtime.h>
#include <hip/hip_bf16.h>

constexpr int HID = 1024;
constexpr int KD  = 16;    // probe directions
constexpr int TM  = 16;    // rows per tile
constexpr int NW  = 8;     // waves per block (each owns a 128-wide col slice)
constexpr int TPB = 8;     // tiles per block (2048 tiles / 256 blocks)

typedef short bf16x8 __attribute__((ext_vector_type(8)));   // MFMA A/B frag
typedef float f32x4  __attribute__((ext_vector_type(4)));   // MFMA C/D frag

__device__ __forceinline__ short f2b(float x) {
    __hip_bfloat16 b = __float2bfloat16(x);
    return *reinterpret_cast<short*>(&b);
}
__device__ __forceinline__ float b2f(short s) {
    return __uint_as_float(((unsigned int)(unsigned short)s) << 16);
}

#define SCHED_FENCE() __builtin_amdgcn_sched_barrier(0)

// Stage one 64KB H tile via global_load_lds: wave w stages rows w*2..w*2+1.
// 16B-piece swizzle ^ (row&7) applied on the GLOBAL source address (LDS dest
// linear, as required); coef ds_read applies the same XOR.
__device__ __forceinline__ void stage_tile(float* ldsBuf, const float* Hbase,
                                           int w, int lane) {
    #pragma unroll
    for (int i = 0; i < 8; ++i) {
        const int rr = w*2 + (i >> 2);
        const int qq = i & 3;
        const int s  = qq*64 + lane;                  // lds piece slot
        const float* g = Hbase + rr*1024 + ((s ^ (rr & 7)) << 2);
        const float* l = ldsBuf + rr*1024 + qq*256;   // wave-uniform base; HW adds lane*16
        __builtin_amdgcn_global_load_lds(
            (const __attribute__((address_space(1))) void*)g,
            (__attribute__((address_space(3))) void*)l, 16, 0, 0);
    }
}

// R20 = R18 (51.1 us, the best) with two deltas:
//  - nt stores REVERTED to plain (R19 post-mortem: each nt instruction covers
//    only an interleaved half of each 128B line -> partial-line amplification,
//    WRITE 131->155-170MB; plain stores let L2 merge to exact 131MB).
//  - prologue reordered: both tile DMAs issue BEFORE the ~48 scattered Q
//    gathers, so the Q round trip hides under the in-flight staging instead
//    of serializing ahead of it.
__global__ __launch_bounds__(NW*64)
void probe_removal_v20(const float* __restrict__ H,
                       const float* __restrict__ Qf,
                       float* __restrict__ out)
{
    const int lane = threadIdx.x & 63;
    const int w    = threadIdx.x >> 6;   // wave: col slice [w*128, w*128+128)
    const int r    = lane & 15;
    const int q    = lane >> 4;

    __shared__ __align__(16) float Hb[2][TM][HID];   // 128 KB double buffer
    __shared__ __align__(16) float ctr[NW][TM][20];  // coef partials
    __shared__ float s2p[NW][TM];

    const int tile0 = blockIdx.x * TPB;

    // ---- prologue staging FIRST: 16 fire-and-forget DMAs in flight ----
    stage_tile(&Hb[0][0][0], H + (size_t)tile0*TM*HID, w, lane);
    SCHED_FENCE();
    stage_tile(&Hb[1][0][0], H + (size_t)(tile0+1)*TM*HID, w, lane);
    SCHED_FENCE();

    // ---- persistent Q fragments gathered while staging is in flight ----
    // coef B-frag: bq[kt][i] = bf16(Q[k][r]), k = w*128 + kt*32 + q*8 + i
    bf16x8 bq[4];
    #pragma unroll
    for (int kt = 0; kt < 4; ++kt)
        #pragma unroll
        for (int i = 0; i < 8; ++i)
            bq[kt][i] = f2b(Qf[(w*128 + kt*32 + q*8 + i)*KD + r]);
    // epilogue A-frags (R13-verified permutation, R15 geometry):
    // pair p: col0 = w*128 + p*32 + (r>>2)*8 + (r&3), col1 = col0 + 4;
    // aq0[p][i] = bf16(Q[col0][q*8+i]) -> two contiguous float4 loads each.
    bf16x8 aq0[4], aq1[4];
    #pragma unroll
    for (int p = 0; p < 4; ++p) {
        if (q < 2) {
            const int col0 = w*128 + p*32 + ((r >> 2) << 3) + (r & 3);
            const float* s0 = Qf + col0*KD + q*8;
            const float* s1 = Qf + (col0 + 4)*KD + q*8;
            const float4 x0 = *reinterpret_cast<const float4*>(s0);
            const float4 y0 = *reinterpret_cast<const float4*>(s0 + 4);
            const float4 x1 = *reinterpret_cast<const float4*>(s1);
            const float4 y1 = *reinterpret_cast<const float4*>(s1 + 4);
            aq0[p][0]=f2b(x0.x); aq0[p][1]=f2b(x0.y); aq0[p][2]=f2b(x0.z); aq0[p][3]=f2b(x0.w);
            aq0[p][4]=f2b(y0.x); aq0[p][5]=f2b(y0.y); aq0[p][6]=f2b(y0.z); aq0[p][7]=f2b(y0.w);
            aq1[p][0]=f2b(x1.x); aq1[p][1]=f2b(x1.y); aq1[p][2]=f2b(x1.z); aq1[p][3]=f2b(x1.w);
            aq1[p][4]=f2b(y1.x); aq1[p][5]=f2b(y1.y); aq1[p][6]=f2b(y1.z); aq1[p][7]=f2b(y1.w);
        } else {
            #pragma unroll
            for (int i = 0; i < 8; ++i) { aq0[p][i] = 0; aq1[p][i] = 0; }
        }
    }
    SCHED_FENCE();

    // Q conversions already forced the compiler to drain the Q loads (and,
    // in-order, the tile-0/1 stages ahead of them) -- one explicit drain:
    asm volatile("s_waitcnt vmcnt(0)" ::: "memory");
    SCHED_FENCE();
    __builtin_amdgcn_s_barrier();

    #pragma unroll
    for (int t = 0; t < TPB; ++t) {
        const int cur = t & 1;
        const char* HbC = (const char*)&Hb[cur][0][0];

        // ---- coef GEMM from LDS (swizzled b128 reads); af = h slice in regs ----
        bf16x8 af[4];
        f32x4 acc0 = {0.f,0.f,0.f,0.f}, acc1 = {0.f,0.f,0.f,0.f};
        float s2 = 0.f;
        #pragma unroll
        for (int kt = 0; kt < 4; ++kt) {
            const int P  = w*32 + kt*8 + q*2;       // even piece index
            const int sx = P ^ (r & 7);
            const float4 x = *(const float4*)(HbC + r*4096 + sx*16);
            const float4 y = *(const float4*)(HbC + r*4096 + (sx^1)*16);
            s2 = fmaf(x.x,x.x, fmaf(x.y,x.y, fmaf(x.z,x.z, fmaf(x.w,x.w, s2))));
            s2 = fmaf(y.x,y.x, fmaf(y.y,y.y, fmaf(y.z,y.z, fmaf(y.w,y.w, s2))));
            bf16x8 a;
            a[0]=f2b(x.x); a[1]=f2b(x.y); a[2]=f2b(x.z); a[3]=f2b(x.w);
            a[4]=f2b(y.x); a[5]=f2b(y.y); a[6]=f2b(y.z); a[7]=f2b(y.w);
            af[kt] = a;
            if (kt & 1) acc1 = __builtin_amdgcn_mfma_f32_16x16x32_bf16(a, bq[kt], acc1, 0, 0, 0);
            else        acc0 = __builtin_amdgcn_mfma_f32_16x16x32_bf16(a, bq[kt], acc0, 0, 0, 0);
        }
        const f32x4 acc = acc0 + acc1;
        s2 += __shfl_xor(s2, 16);
        s2 += __shfl_xor(s2, 32);

        #pragma unroll
        for (int i = 0; i < 4; ++i) ctr[w][q*4 + i][r] = acc[i];
        if (q == 0) s2p[w][r] = s2;

        // ctr visible to all waves; raw barrier does NOT drain vmcnt:
        asm volatile("s_waitcnt lgkmcnt(0)" ::: "memory");
        SCHED_FENCE();
        __builtin_amdgcn_s_barrier();
        SCHED_FENCE();

        // ---- stage tile t+2 into the freed buffer ----
        if (t + 2 < TPB)
            stage_tile(&Hb[cur][0][0], H + (size_t)(tile0+t+2)*TM*HID, w, lane);
        SCHED_FENCE();

        // ---- cross-wave reduce -> coefs, scale, pb ----
        float cf[8] = {0,0,0,0,0,0,0,0};
        if (q < 2) {
            #pragma unroll
            for (int w2 = 0; w2 < NW; ++w2) {
                const float4 a = *reinterpret_cast<const float4*>(&ctr[w2][r][q*8]);
                const float4 b = *reinterpret_cast<const float4*>(&ctr[w2][r][q*8 + 4]);
                cf[0]+=a.x; cf[1]+=a.y; cf[2]+=a.z; cf[3]+=a.w;
                cf[4]+=b.x; cf[5]+=b.y; cf[6]+=b.z; cf[7]+=b.w;
            }
        }
        float s2tot = 0.f;
        #pragma unroll
        for (int w2 = 0; w2 < NW; ++w2) s2tot += s2p[w2][r];

        float sc2 = 0.f;
        #pragma unroll
        for (int i = 0; i < 8; ++i) sc2 = fmaf(cf[i], cf[i], sc2);
        sc2 += __shfl_xor(sc2, 16);
        sc2 += __shfl_xor(sc2, 32);
        const float scale = rsqrtf(fmaxf(1.0f - sc2 / s2tot, 1e-20f));

        bf16x8 pb;
        #pragma unroll
        for (int i = 0; i < 8; ++i) pb[i] = f2b(cf[i]);

        // ---- fused epilogue: all operands in registers; 8 PLAIN stores/lane
        //      (L2 merges the o0/o1 interleaved halves into full 128B lines) ----
        float* orow = out + (size_t)(tile0+t)*TM*HID + r*HID + w*128;
        const f32x4 zero4 = {0.f,0.f,0.f,0.f};
        #pragma unroll
        for (int p = 0; p < 4; ++p) {
            const f32x4 d0 = __builtin_amdgcn_mfma_f32_16x16x32_bf16(aq0[p], pb, zero4, 0, 0, 0);
            const f32x4 d1 = __builtin_amdgcn_mfma_f32_16x16x32_bf16(aq1[p], pb, zero4, 0, 0, 0);
            f32x4 o0, o1;
            #pragma unroll
            for (int ii = 0; ii < 4; ++ii) {
                o0[ii] = (b2f(af[p][ii])     - d0[ii]) * scale;
                o1[ii] = (b2f(af[p][4 + ii]) - d1[ii]) * scale;
            }
            *reinterpret_cast<f32x4*>(orow + p*32 + q*8)     = o0;
            *reinterpret_cast<f32x4*>(orow + p*32 + q*8 + 4) = o1;
        }
        SCHED_FENCE();

        // ---- counted drain: stage(t+1) landed; stage(t+2)+stores(t) stay
        //      in flight (never vmcnt(0) mid-loop) ----
        if (t < TPB-1) {
            asm volatile("s_waitcnt vmcnt(16)" ::: "memory");
            SCHED_FENCE();
            __builtin_amdgcn_s_barrier();
            SCHED_FENCE();
        }
    }
}

extern "C" void kernel_launch(void* const* d_in, const int* in_sizes, int n_in,
                              void* d_out, int out_size, void* d_ws, size_t ws_size,
                              hipStream_t stream) {
    const float* H  = (const float*)d_in[0];   // [8,4096,1024] f32
    const float* Qf = (const float*)d_in[1];   // [1024,16] f32, orthonormal cols
    float* outp     = (float*)d_out;
    const int nrows  = in_sizes[0] / HID;      // 32768
    const int ntiles = nrows / TM;             // 2048

    // SINGLE launch: 139KB LDS -> 1 block/CU, 256 blocks x 8 tiles, DMA pipeline
    hipLaunchKernelGGL(probe_removal_v20, dim3(ntiles / TPB), dim3(NW*64), 0, stream,
                       H, Qf, outp);
}

// Round 21
// 51.109 us; speedup vs baseline: 1.1538x; 1.0493x over previous
//
#include <hip/hip_runtime.h>
#include <hip/hip_bf16.h>

constexpr int HID = 1024;
constexpr int KD  = 16;    // probe directions
constexpr int TM  = 16;    // rows per tile
constexpr int NW  = 8;     // waves per block (each owns a 128-wide col slice)
constexpr int TPB = 8;     // tiles per block (2048 tiles / 256 blocks)

typedef short bf16x8 __attribute__((ext_vector_type(8)));   // MFMA A/B frag
typedef float f32x4  __attribute__((ext_vector_type(4)));   // MFMA C/D frag

__device__ __forceinline__ short f2b(float x) {
    __hip_bfloat16 b = __float2bfloat16(x);
    return *reinterpret_cast<short*>(&b);
}
__device__ __forceinline__ float b2f(short s) {
    return __uint_as_float(((unsigned int)(unsigned short)s) << 16);
}

#define SCHED_FENCE() __builtin_amdgcn_sched_barrier(0)

// Stage one 64KB H tile via global_load_lds: wave w stages rows w*2..w*2+1.
// 16B-piece swizzle ^ (row&7) applied on the GLOBAL source address (LDS dest
// linear, as required); coef ds_read applies the same XOR.
__device__ __forceinline__ void stage_tile(float* ldsBuf, const float* Hbase,
                                           int w, int lane) {
    #pragma unroll
    for (int i = 0; i < 8; ++i) {
        const int rr = w*2 + (i >> 2);
        const int qq = i & 3;
        const int s  = qq*64 + lane;                  // lds piece slot
        const float* g = Hbase + rr*1024 + ((s ^ (rr & 7)) << 2);
        const float* l = ldsBuf + rr*1024 + qq*256;   // wave-uniform base; HW adds lane*16
        __builtin_amdgcn_global_load_lds(
            (const __attribute__((address_space(1))) void*)g,
            (__attribute__((address_space(3))) void*)l, 16, 0, 0);
    }
}

// FINAL (= R18, best measured 51.1 us): single launch, fused epilogue (h
// carried in registers from the coef phase -- zero H re-reads), DMA-staged
// double-buffered LDS with counted vmcnt (never 0 mid-loop), plain stores
// (L2 merges interleaved halves into exact full-line writebacks).
// R19 (nt stores) and R20 (prologue reorder) both regressed; reverted.
__global__ __launch_bounds__(NW*64)
void probe_removal_one(const float* __restrict__ H,
                       const float* __restrict__ Qf,
                       float* __restrict__ out)
{
    const int lane = threadIdx.x & 63;
    const int w    = threadIdx.x >> 6;   // wave: col slice [w*128, w*128+128)
    const int r    = lane & 15;
    const int q    = lane >> 4;

    __shared__ __align__(16) float Hb[2][TM][HID];   // 128 KB double buffer
    __shared__ __align__(16) float ctr[NW][TM][20];  // coef partials
    __shared__ float s2p[NW][TM];

    const int tile0 = blockIdx.x * TPB;

    // ---- persistent Q fragments gathered directly from Qf (no workspace) ----
    // coef B-frag: bq[kt][i] = bf16(Q[k][r]), k = w*128 + kt*32 + q*8 + i
    bf16x8 bq[4];
    #pragma unroll
    for (int kt = 0; kt < 4; ++kt)
        #pragma unroll
        for (int i = 0; i < 8; ++i)
            bq[kt][i] = f2b(Qf[(w*128 + kt*32 + q*8 + i)*KD + r]);
    // epilogue A-frags (R13-verified permutation, R15 geometry):
    // pair p: col0 = w*128 + p*32 + (r>>2)*8 + (r&3), col1 = col0 + 4;
    // aq0[p][i] = bf16(Q[col0][q*8+i]) -> two contiguous float4 loads each.
    bf16x8 aq0[4], aq1[4];
    #pragma unroll
    for (int p = 0; p < 4; ++p) {
        if (q < 2) {
            const int col0 = w*128 + p*32 + ((r >> 2) << 3) + (r & 3);
            const float* s0 = Qf + col0*KD + q*8;
            const float* s1 = Qf + (col0 + 4)*KD + q*8;
            const float4 x0 = *reinterpret_cast<const float4*>(s0);
            const float4 y0 = *reinterpret_cast<const float4*>(s0 + 4);
            const float4 x1 = *reinterpret_cast<const float4*>(s1);
            const float4 y1 = *reinterpret_cast<const float4*>(s1 + 4);
            aq0[p][0]=f2b(x0.x); aq0[p][1]=f2b(x0.y); aq0[p][2]=f2b(x0.z); aq0[p][3]=f2b(x0.w);
            aq0[p][4]=f2b(y0.x); aq0[p][5]=f2b(y0.y); aq0[p][6]=f2b(y0.z); aq0[p][7]=f2b(y0.w);
            aq1[p][0]=f2b(x1.x); aq1[p][1]=f2b(x1.y); aq1[p][2]=f2b(x1.z); aq1[p][3]=f2b(x1.w);
            aq1[p][4]=f2b(y1.x); aq1[p][5]=f2b(y1.y); aq1[p][6]=f2b(y1.z); aq1[p][7]=f2b(y1.w);
        } else {
            #pragma unroll
            for (int i = 0; i < 8; ++i) { aq0[p][i] = 0; aq1[p][i] = 0; }
        }
    }
    SCHED_FENCE();

    // ---- prologue: stage tiles 0 and 1 (8 loads each per wave) ----
    stage_tile(&Hb[0][0][0], H + (size_t)tile0*TM*HID, w, lane);
    SCHED_FENCE();
    stage_tile(&Hb[1][0][0], H + (size_t)(tile0+1)*TM*HID, w, lane);
    SCHED_FENCE();
    asm volatile("s_waitcnt vmcnt(8)" ::: "memory");   // tile 0 landed (tile 1 in flight)
    SCHED_FENCE();
    __builtin_amdgcn_s_barrier();

    #pragma unroll
    for (int t = 0; t < TPB; ++t) {
        const int cur = t & 1;
        const char* HbC = (const char*)&Hb[cur][0][0];

        // ---- coef GEMM from LDS (swizzled b128 reads); af = h slice in regs ----
        bf16x8 af[4];
        f32x4 acc0 = {0.f,0.f,0.f,0.f}, acc1 = {0.f,0.f,0.f,0.f};
        float s2 = 0.f;
        #pragma unroll
        for (int kt = 0; kt < 4; ++kt) {
            const int P  = w*32 + kt*8 + q*2;       // even piece index
            const int sx = P ^ (r & 7);
            const float4 x = *(const float4*)(HbC + r*4096 + sx*16);
            const float4 y = *(const float4*)(HbC + r*4096 + (sx^1)*16);
            s2 = fmaf(x.x,x.x, fmaf(x.y,x.y, fmaf(x.z,x.z, fmaf(x.w,x.w, s2))));
            s2 = fmaf(y.x,y.x, fmaf(y.y,y.y, fmaf(y.z,y.z, fmaf(y.w,y.w, s2))));
            bf16x8 a;
            a[0]=f2b(x.x); a[1]=f2b(x.y); a[2]=f2b(x.z); a[3]=f2b(x.w);
            a[4]=f2b(y.x); a[5]=f2b(y.y); a[6]=f2b(y.z); a[7]=f2b(y.w);
            af[kt] = a;
            if (kt & 1) acc1 = __builtin_amdgcn_mfma_f32_16x16x32_bf16(a, bq[kt], acc1, 0, 0, 0);
            else        acc0 = __builtin_amdgcn_mfma_f32_16x16x32_bf16(a, bq[kt], acc0, 0, 0, 0);
        }
        const f32x4 acc = acc0 + acc1;
        s2 += __shfl_xor(s2, 16);
        s2 += __shfl_xor(s2, 32);

        #pragma unroll
        for (int i = 0; i < 4; ++i) ctr[w][q*4 + i][r] = acc[i];
        if (q == 0) s2p[w][r] = s2;

        // ctr visible to all waves; raw barrier does NOT drain vmcnt:
        asm volatile("s_waitcnt lgkmcnt(0)" ::: "memory");
        SCHED_FENCE();
        __builtin_amdgcn_s_barrier();
        SCHED_FENCE();

        // ---- stage tile t+2 into the freed buffer ----
        if (t + 2 < TPB)
            stage_tile(&Hb[cur][0][0], H + (size_t)(tile0+t+2)*TM*HID, w, lane);
        SCHED_FENCE();

        // ---- cross-wave reduce -> coefs, scale, pb ----
        float cf[8] = {0,0,0,0,0,0,0,0};
        if (q < 2) {
            #pragma unroll
            for (int w2 = 0; w2 < NW; ++w2) {
                const float4 a = *reinterpret_cast<const float4*>(&ctr[w2][r][q*8]);
                const float4 b = *reinterpret_cast<const float4*>(&ctr[w2][r][q*8 + 4]);
                cf[0]+=a.x; cf[1]+=a.y; cf[2]+=a.z; cf[3]+=a.w;
                cf[4]+=b.x; cf[5]+=b.y; cf[6]+=b.z; cf[7]+=b.w;
            }
        }
        float s2tot = 0.f;
        #pragma unroll
        for (int w2 = 0; w2 < NW; ++w2) s2tot += s2p[w2][r];

        float sc2 = 0.f;
        #pragma unroll
        for (int i = 0; i < 8; ++i) sc2 = fmaf(cf[i], cf[i], sc2);
        sc2 += __shfl_xor(sc2, 16);
        sc2 += __shfl_xor(sc2, 32);
        const float scale = rsqrtf(fmaxf(1.0f - sc2 / s2tot, 1e-20f));

        bf16x8 pb;
        #pragma unroll
        for (int i = 0; i < 8; ++i) pb[i] = f2b(cf[i]);

        // ---- fused epilogue: all operands in registers; 8 stores per lane ----
        float* orow = out + (size_t)(tile0+t)*TM*HID + r*HID + w*128;
        const f32x4 zero4 = {0.f,0.f,0.f,0.f};
        #pragma unroll
        for (int p = 0; p < 4; ++p) {
            const f32x4 d0 = __builtin_amdgcn_mfma_f32_16x16x32_bf16(aq0[p], pb, zero4, 0, 0, 0);
            const f32x4 d1 = __builtin_amdgcn_mfma_f32_16x16x32_bf16(aq1[p], pb, zero4, 0, 0, 0);
            f32x4 o0, o1;
            #pragma unroll
            for (int ii = 0; ii < 4; ++ii) {
                o0[ii] = (b2f(af[p][ii])     - d0[ii]) * scale;
                o1[ii] = (b2f(af[p][4 + ii]) - d1[ii]) * scale;
            }
            *reinterpret_cast<f32x4*>(orow + p*32 + q*8)     = o0;
            *reinterpret_cast<f32x4*>(orow + p*32 + q*8 + 4) = o1;
        }
        SCHED_FENCE();

        // ---- counted drain: stage(t+1) landed; stage(t+2)+stores(t) stay
        //      in flight (never vmcnt(0) mid-loop) ----
        if (t < TPB-1) {
            asm volatile("s_waitcnt vmcnt(16)" ::: "memory");
            SCHED_FENCE();
            __builtin_amdgcn_s_barrier();
            SCHED_FENCE();
        }
    }
}

extern "C" void kernel_launch(void* const* d_in, const int* in_sizes, int n_in,
                              void* d_out, int out_size, void* d_ws, size_t ws_size,
                              hipStream_t stream) {
    const float* H  = (const float*)d_in[0];   // [8,4096,1024] f32
    const float* Qf = (const float*)d_in[1];   // [1024,16] f32, orthonormal cols
    float* outp     = (float*)d_out;
    const int nrows  = in_sizes[0] / HID;      // 32768
    const int ntiles = nrows / TM;             // 2048

    // SINGLE launch: 139KB LDS -> 1 block/CU, 256 blocks x 8 tiles, DMA pipeline
    hipLaunchKernelGGL(probe_removal_one, dim3(ntiles / TPB), dim3(NW*64), 0, stream,
                       H, Qf, outp);
}